// Round 10
// baseline (41.853 us; speedup 1.0000x reference)
//
#include <hip/hip_runtime.h>

typedef __attribute__((ext_vector_type(8))) short short8;
typedef __attribute__((ext_vector_type(16))) float floatx16;

// B1 frag layout: per sid, q = (ds*9 + j)*4 + nc  (ds in [0,16), j in [0,9), nc in [0,4))
//   uint4 slot = q*128 + p*64 + l   (p = 0 hi, 1 lo; l = lane)
// B2 frag layout: per sid, q2 = (w*9 + j)*2 + nc (w in [0,8), nc in [0,2))
//   uint4 slot = q2*128 + p*64 + l

__device__ __forceinline__ unsigned short f2bf(float f) {
  union { float f; unsigned u; } v; v.f = f;
  unsigned r = v.u + 0x7fffu + ((v.u >> 16) & 1u);
  return (unsigned short)(r >> 16);
}
__device__ __forceinline__ float bf2f(unsigned short h) {
  union { unsigned u; float f; } v; v.u = ((unsigned)h) << 16;
  return v.f;
}

__global__ __launch_bounds__(512) void prep_frags(
    const float* __restrict__ bw1x, const float* __restrict__ sw1x,
    const float* __restrict__ bb1x, const float* __restrict__ sb1x,
    const float* __restrict__ bw2x, const float* __restrict__ sw2x,
    const float* __restrict__ bb2x, const float* __restrict__ sb2x,
    const float* __restrict__ bw1y, const float* __restrict__ sw1y,
    const float* __restrict__ bb1y, const float* __restrict__ sb1y,
    const float* __restrict__ bw2y, const float* __restrict__ sw2y,
    const float* __restrict__ bb2y, const float* __restrict__ sb2y,
    uint4* __restrict__ B1fx, uint4* __restrict__ B1fy,
    uint4* __restrict__ B2fx, uint4* __restrict__ B2fy,
    float* __restrict__ b1x, float* __restrict__ b1y,
    float* __restrict__ b2x, float* __restrict__ b2y,
    int* __restrict__ cnt)
{
  int idx = blockIdx.x * 512 + threadIdx.x;
  if (idx < 2 * 36864) {                       // B1: 2 sids x 576 q x 64 l
    int sid = idx / 36864;
    int rem = idx - sid * 36864;
    int q = rem >> 6, l = rem & 63;
    int nc = q & 3, t9 = q >> 2;
    int j = t9 % 9, ds = t9 / 9;
    const float* bw = sid ? bw1y : bw1x;
    const float* sw = sid ? sw1y : sw1x;
    uint4* dst = sid ? B1fy : B1fx;
    int o = nc * 32 + (l & 31);
    int dbase = ds * 16 + (l >> 5) * 8;
    unsigned short eh[8], el[8];
    #pragma unroll
    for (int i = 0; i < 8; ++i) {
      int d = dbase + i;
      float wv = (j == 0) ? bw[o * 256 + d] : sw[o * 2048 + d * 8 + (j - 1)];
      unsigned short hi = f2bf(wv);
      eh[i] = hi;
      el[i] = f2bf(wv - bf2f(hi));
    }
    uint4 oh, ol;
    oh.x = (unsigned)eh[0] | ((unsigned)eh[1] << 16);
    oh.y = (unsigned)eh[2] | ((unsigned)eh[3] << 16);
    oh.z = (unsigned)eh[4] | ((unsigned)eh[5] << 16);
    oh.w = (unsigned)eh[6] | ((unsigned)eh[7] << 16);
    ol.x = (unsigned)el[0] | ((unsigned)el[1] << 16);
    ol.y = (unsigned)el[2] | ((unsigned)el[3] << 16);
    ol.z = (unsigned)el[4] | ((unsigned)el[5] << 16);
    ol.w = (unsigned)el[6] | ((unsigned)el[7] << 16);
    dst[q * 128 + l]      = oh;
    dst[q * 128 + 64 + l] = ol;
  } else if (idx < 2 * 36864 + 2 * 9216) {     // B2: 2 sids x 144 q2 x 64 l
    int i2 = idx - 2 * 36864;
    int sid = i2 / 9216;
    int rem = i2 - sid * 9216;
    int q2 = rem >> 6, l = rem & 63;
    int nc = q2 & 1, t9 = q2 >> 1;
    int j = t9 % 9, w = t9 / 9;
    const float* bw = sid ? bw2y : bw2x;
    const float* sw = sid ? sw2y : sw2x;
    uint4* dst = sid ? B2fy : B2fx;
    int o = nc * 32 + (l & 31);
    int dbase = w * 16 + (l >> 5) * 8;
    unsigned short eh[8], el[8];
    #pragma unroll
    for (int i = 0; i < 8; ++i) {
      int d = dbase + i;
      float wv = (j == 0) ? bw[o * 128 + d] : sw[o * 1024 + d * 8 + (j - 1)];
      unsigned short hi = f2bf(wv);
      eh[i] = hi;
      el[i] = f2bf(wv - bf2f(hi));
    }
    uint4 oh, ol;
    oh.x = (unsigned)eh[0] | ((unsigned)eh[1] << 16);
    oh.y = (unsigned)eh[2] | ((unsigned)eh[3] << 16);
    oh.z = (unsigned)eh[4] | ((unsigned)eh[5] << 16);
    oh.w = (unsigned)eh[6] | ((unsigned)eh[7] << 16);
    ol.x = (unsigned)el[0] | ((unsigned)el[1] << 16);
    ol.y = (unsigned)el[2] | ((unsigned)el[3] << 16);
    ol.z = (unsigned)el[4] | ((unsigned)el[5] << 16);
    ol.w = (unsigned)el[6] | ((unsigned)el[7] << 16);
    dst[q2 * 128 + l]      = oh;
    dst[q2 * 128 + 64 + l] = ol;
  } else {
    int i2 = idx - (2 * 36864 + 2 * 9216);
    if (i2 < 128)      b1x[i2]       = bb1x[i2]       + sb1x[i2];
    else if (i2 < 256) b1y[i2 - 128] = bb1y[i2 - 128] + sb1y[i2 - 128];
    else if (i2 < 320) b2x[i2 - 256] = bb2x[i2 - 256] + sb2x[i2 - 256];
    else if (i2 < 384) b2y[i2 - 320] = bb2y[i2 - 320] + sb2y[i2 - 320];
    else if (i2 < 388) cnt[i2 - 384] = 0;
  }
}

// ---------- fused: both layers + last-block finish; block = (sid, 32-row tile m)
__global__ __launch_bounds__(512, 2) void fused_kernel(
    const float* __restrict__ Xx, const float* __restrict__ Xy,
    const uint4* __restrict__ B1fx, const uint4* __restrict__ B1fy,
    const uint4* __restrict__ B2fx, const uint4* __restrict__ B2fy,
    const float* __restrict__ b1x_, const float* __restrict__ b1y_,
    const float* __restrict__ b2x_, const float* __restrict__ b2y_,
    const float* __restrict__ finw, const float* __restrict__ finb,
    float* __restrict__ partial, int* __restrict__ cnt,
    float* __restrict__ out)
{
  __shared__ __align__(16) char smem[51232];
  float* xsh  = (float*)smem;               // 32*264 floats = 33792 B
  float* S0   = (float*)smem;               // 16 KB (alias; used after xr read)
  float* S1   = (float*)(smem + 16384);     // 16 KB
  float* h1s  = (float*)(smem + 33792);     // 32*136 floats = 17408 B
  float* redw = (float*)(smem + 51200);     // 8 floats

  const int t    = threadIdx.x;
  const int bid  = blockIdx.x;
  const int sid  = bid >> 7;
  const int m    = bid & 127;
  const int wave = t >> 6;
  const int l    = t & 63;
  const int lc   = l & 31;
  const int lk   = l >> 5;

  const float* X  = sid ? Xy : Xx;
  const uint4* B1 = sid ? B1fy : B1fx;
  const uint4* B2 = sid ? B2fy : B2fx;
  const float* b1 = sid ? b1y_ : b1x_;
  const float* b2 = sid ? b2y_ : b2x_;

  // ---- stage x tile: 32 rows x 256, coalesced ----
  {
    int row = t >> 4, col = (t & 15) * 16;
    const float* src = X + (size_t)(m * 32 + row) * 256 + col;
    #pragma unroll
    for (int q = 0; q < 4; ++q)
      *(float4*)(xsh + row * 264 + col + q * 4) = *(const float4*)(src + q * 4);
  }
  __syncthreads();

  // per-lane A data: row lc, dims for ds0 = 2*wave and ds1 = 2*wave+1
  float xr0[8], xr1[8];
  {
    int cb = wave * 32 + lk * 8;
    float4 v0 = *(const float4*)(xsh + lc * 264 + cb);
    float4 v1 = *(const float4*)(xsh + lc * 264 + cb + 4);
    float4 u0 = *(const float4*)(xsh + lc * 264 + cb + 16);
    float4 u1 = *(const float4*)(xsh + lc * 264 + cb + 20);
    xr0[0]=v0.x; xr0[1]=v0.y; xr0[2]=v0.z; xr0[3]=v0.w;
    xr0[4]=v1.x; xr0[5]=v1.y; xr0[6]=v1.z; xr0[7]=v1.w;
    xr1[0]=u0.x; xr1[1]=u0.y; xr1[2]=u0.z; xr1[3]=u0.w;
    xr1[4]=u1.x; xr1[5]=u1.y; xr1[6]=u1.z; xr1[7]=u1.w;
  }
  __syncthreads();   // xsh dead; S0/S1 free

  // ================= layer 1: 18 steps (9 j x 2 ds), 1-step lookahead ========
  floatx16 acc[4] = {};

  auto loadB1 = [&](int s, uint4* bf) {
    int j = s >> 1, ds = wave * 2 + (s & 1);
    const uint4* bp = B1 + (size_t)((ds * 9 + j) * 4) * 128 + l;
    #pragma unroll
    for (int nc = 0; nc < 4; ++nc) {
      bf[nc * 2]     = bp[nc * 128];
      bf[nc * 2 + 1] = bp[nc * 128 + 64];
    }
  };
  auto computeB1 = [&](int s, const uint4* bf) {
    int j = s >> 1;
    const float* xr = (s & 1) ? xr1 : xr0;
    float f[8];
    if (j == 0) {
      #pragma unroll
      for (int i = 0; i < 8; ++i)
        f[i] = __fdividef(xr[i], 1.f + __expf(-xr[i]));
    } else {
      float g = -2.f + (float)(j - 1) * (4.f / 7.f);
      #pragma unroll
      for (int i = 0; i < 8; ++i) {
        float z = (xr[i] - g) * 1.75f;
        f[i] = __expf(-z * z);
      }
    }
    short8 a;
    #pragma unroll
    for (int i = 0; i < 8; ++i) a[i] = (short)f2bf(f[i]);
    #pragma unroll
    for (int nc = 0; nc < 4; ++nc) {
      short8 bh = __builtin_bit_cast(short8, bf[nc * 2]);
      short8 bl = __builtin_bit_cast(short8, bf[nc * 2 + 1]);
      acc[nc] = __builtin_amdgcn_mfma_f32_32x32x16_bf16(a, bh, acc[nc], 0, 0, 0);
      acc[nc] = __builtin_amdgcn_mfma_f32_32x32x16_bf16(a, bl, acc[nc], 0, 0, 0);
    }
  };

  {
    uint4 bfE[8], bfO[8];
    loadB1(0, bfE);
    #pragma unroll 1
    for (int s = 0; s < 18; s += 2) {
      loadB1(s + 1, bfO);
      computeB1(s, bfE);
      if (s + 2 < 18) loadB1(s + 2, bfE);
      computeB1(s + 1, bfO);
    }
  }

  // ---- cross-wave K reduction: race-free 2-buffer tree (32x128 tile) ----
  auto st = [&](float* Sb) {
    #pragma unroll
    for (int nc = 0; nc < 4; ++nc)
      #pragma unroll
      for (int r = 0; r < 16; ++r) {
        int row = (r & 3) + 8 * (r >> 2) + 4 * lk;
        Sb[row * 128 + nc * 32 + lc] = acc[nc][r];
      }
  };
  auto ad = [&](const float* Sb) {
    #pragma unroll
    for (int nc = 0; nc < 4; ++nc)
      #pragma unroll
      for (int r = 0; r < 16; ++r) {
        int row = (r & 3) + 8 * (r >> 2) + 4 * lk;
        acc[nc][r] += Sb[row * 128 + nc * 32 + lc];
      }
  };
  __syncthreads();
  if (wave == 1) st(S0);
  if (wave == 3) st(S1);
  __syncthreads();
  if (wave == 0) ad(S0);
  if (wave == 2) ad(S1);
  __syncthreads();
  if (wave == 5) st(S0);
  if (wave == 7) st(S1);
  __syncthreads();
  if (wave == 4) ad(S0);
  if (wave == 6) ad(S1);
  __syncthreads();
  if (wave == 2) st(S0);
  if (wave == 6) st(S1);
  __syncthreads();
  if (wave == 0) ad(S0);
  if (wave == 4) ad(S1);
  __syncthreads();
  if (wave == 4) st(S0);
  __syncthreads();
  if (wave == 0) {
    ad(S0);
    #pragma unroll
    for (int nc = 0; nc < 4; ++nc)
      #pragma unroll
      for (int r = 0; r < 16; ++r) {
        int row = (r & 3) + 8 * (r >> 2) + 4 * lk;
        int col = nc * 32 + lc;
        h1s[row * 136 + col] = acc[nc][r] + b1[col];
      }
  }
  __syncthreads();

  // ================= layer 2: 9 steps, 1-step lookahead =================
  floatx16 acc2[2] = {};

  auto loadB2 = [&](int s, uint4* cf) {
    const uint4* bp = B2 + (size_t)((wave * 9 + s) * 2) * 128 + l;
    #pragma unroll
    for (int nc = 0; nc < 2; ++nc) {
      cf[nc * 2]     = bp[nc * 128];
      cf[nc * 2 + 1] = bp[nc * 128 + 64];
    }
  };

  uint4 cfE[4], cfO[4];
  loadB2(0, cfE);              // issue before h1 read; independent

  float hr[8];
  {
    int cb = wave * 16 + lk * 8;
    float4 v0 = *(const float4*)(h1s + lc * 136 + cb);
    float4 v1 = *(const float4*)(h1s + lc * 136 + cb + 4);
    hr[0]=v0.x; hr[1]=v0.y; hr[2]=v0.z; hr[3]=v0.w;
    hr[4]=v1.x; hr[5]=v1.y; hr[6]=v1.z; hr[7]=v1.w;
  }

  auto computeB2 = [&](int s, const uint4* cf) {
    float f[8];
    if (s == 0) {
      #pragma unroll
      for (int i = 0; i < 8; ++i)
        f[i] = __fdividef(hr[i], 1.f + __expf(-hr[i]));
    } else {
      float g = -2.f + (float)(s - 1) * (4.f / 7.f);
      #pragma unroll
      for (int i = 0; i < 8; ++i) {
        float z = (hr[i] - g) * 1.75f;
        f[i] = __expf(-z * z);
      }
    }
    short8 a;
    #pragma unroll
    for (int i = 0; i < 8; ++i) a[i] = (short)f2bf(f[i]);
    #pragma unroll
    for (int nc = 0; nc < 2; ++nc) {
      short8 bh = __builtin_bit_cast(short8, cf[nc * 2]);
      short8 bl = __builtin_bit_cast(short8, cf[nc * 2 + 1]);
      acc2[nc] = __builtin_amdgcn_mfma_f32_32x32x16_bf16(a, bh, acc2[nc], 0, 0, 0);
      acc2[nc] = __builtin_amdgcn_mfma_f32_32x32x16_bf16(a, bl, acc2[nc], 0, 0, 0);
    }
  };

  #pragma unroll 1
  for (int s = 0; s < 8; s += 2) {
    loadB2(s + 1, cfO);
    computeB2(s, cfE);
    loadB2(s + 2, cfE);
    computeB2(s + 1, cfO);
  }
  computeB2(8, cfE);

  // ---- per-wave dot with final_w; cross-wave scalar sum ----
  const float* wf = finw + sid * 64;
  {
    float w0 = wf[lc], w1v = wf[32 + lc];
    float pz = 0.f;
    #pragma unroll
    for (int r = 0; r < 16; ++r) pz += acc2[0][r] * w0 + acc2[1][r] * w1v;
    #pragma unroll
    for (int off = 32; off > 0; off >>= 1) pz += __shfl_down(pz, off, 64);
    if (l == 0) redw[wave] = pz;
  }
  __syncthreads();

  // ---- block partial + last-block-per-batch finish ----
  if (wave == 0) {
    const int b    = m >> 5;                 // batch
    const int slot = sid * 32 + (m & 31);    // 64 slots per batch
    float v = (l < 8) ? redw[l] : 0.f;
    v += 32.f * b2[l] * wf[l];               // bias term over this block's 32 rows
    #pragma unroll
    for (int off = 32; off > 0; off >>= 1) v += __shfl_down(v, off, 64);
    int old = 0;
    if (l == 0) {
      partial[b * 64 + slot] = v;
      __threadfence();
      old = atomicAdd(&cnt[b], 1);
    }
    int bc = __shfl(old, 0, 64);
    if (bc == 63) {                          // last block of this batch
      float pv = atomicAdd(&partial[b * 64 + l], 0.f);  // coherent read
      #pragma unroll
      for (int off = 32; off > 0; off >>= 1) pv += __shfl_down(pv, off, 64);
      if (l == 0) out[b] = finb[0] + pv * (1.0f / 1024.0f);
    }
  }
}

extern "C" void kernel_launch(void* const* d_in, const int* in_sizes, int n_in,
                              void* d_out, int out_size, void* d_ws, size_t ws_size,
                              hipStream_t stream)
{
  (void)in_sizes; (void)n_in; (void)out_size; (void)ws_size;
  const float* x    = (const float*)d_in[0];
  const float* y    = (const float*)d_in[1];
  const float* bw1x = (const float*)d_in[2];
  const float* bb1x = (const float*)d_in[3];
  const float* sw1x = (const float*)d_in[4];
  const float* sb1x = (const float*)d_in[5];
  const float* bw2x = (const float*)d_in[6];
  const float* bb2x = (const float*)d_in[7];
  const float* sw2x = (const float*)d_in[8];
  const float* sb2x = (const float*)d_in[9];
  const float* bw1y = (const float*)d_in[10];
  const float* bb1y = (const float*)d_in[11];
  const float* sw1y = (const float*)d_in[12];
  const float* sb1y = (const float*)d_in[13];
  const float* bw2y = (const float*)d_in[14];
  const float* bb2y = (const float*)d_in[15];
  const float* sw2y = (const float*)d_in[16];
  const float* sb2y = (const float*)d_in[17];
  const float* finw = (const float*)d_in[18];
  const float* finb = (const float*)d_in[19];

  char* ws = (char*)d_ws;
  uint4* B1fx = (uint4*)(ws);                       // 1179648 B
  uint4* B1fy = (uint4*)(ws + 1179648);
  uint4* B2fx = (uint4*)(ws + 2359296);             // 294912 B
  uint4* B2fy = (uint4*)(ws + 2654208);
  float* b1x  = (float*)(ws + 2949120);
  float* b1y  = b1x + 128;
  float* b2x  = b1y + 128;
  float* b2y  = b2x + 64;
  float* partial = b2y + 64;                        // 256 floats
  int*   cnt  = (int*)(partial + 256);              // 4 ints

  int prep_total = 2 * 36864 + 2 * 9216 + 388;      // 92548
  int prep_blocks = (prep_total + 511) / 512;
  hipLaunchKernelGGL(prep_frags, dim3(prep_blocks), dim3(512), 0, stream,
                     bw1x, sw1x, bb1x, sb1x, bw2x, sw2x, bb2x, sb2x,
                     bw1y, sw1y, bb1y, sb1y, bw2y, sw2y, bb2y, sb2y,
                     B1fx, B1fy, B2fx, B2fy, b1x, b1y, b2x, b2y, cnt);

  hipLaunchKernelGGL(fused_kernel, dim3(256), dim3(512), 0, stream,
                     x, y, B1fx, B1fy, B2fx, B2fy, b1x, b1y, b2x, b2y,
                     finw, finb, partial, cnt, (float*)d_out);
}

// Round 11
// 32.537 us; speedup vs baseline: 1.2863x; 1.2863x over previous
//
#include <hip/hip_runtime.h>

typedef __attribute__((ext_vector_type(8))) short short8;
typedef __attribute__((ext_vector_type(16))) float floatx16;

// B1 frag layout (hi-only): per sid, q = (ds*9 + j)*4 + nc  (ds<16, j<9, nc<4)
//   uint4 slot = q*64 + l   (l = lane)
// B2 frag layout: per sid, q2 = (w*9 + j)*2 + nc (w<8, nc<2); slot = q2*64 + l

__device__ __forceinline__ unsigned short f2bf(float f) {
  union { float f; unsigned u; } v; v.f = f;
  unsigned r = v.u + 0x7fffu + ((v.u >> 16) & 1u);
  return (unsigned short)(r >> 16);
}

__global__ __launch_bounds__(512) void prep_frags(
    const float* __restrict__ bw1x, const float* __restrict__ sw1x,
    const float* __restrict__ bb1x, const float* __restrict__ sb1x,
    const float* __restrict__ bw2x, const float* __restrict__ sw2x,
    const float* __restrict__ bb2x, const float* __restrict__ sb2x,
    const float* __restrict__ bw1y, const float* __restrict__ sw1y,
    const float* __restrict__ bb1y, const float* __restrict__ sb1y,
    const float* __restrict__ bw2y, const float* __restrict__ sw2y,
    const float* __restrict__ bb2y, const float* __restrict__ sb2y,
    uint4* __restrict__ B1fx, uint4* __restrict__ B1fy,
    uint4* __restrict__ B2fx, uint4* __restrict__ B2fy,
    float* __restrict__ b1x, float* __restrict__ b1y,
    float* __restrict__ b2x, float* __restrict__ b2y,
    int* __restrict__ cnt)
{
  int idx = blockIdx.x * 512 + threadIdx.x;
  if (idx < 2 * 36864) {                       // B1: 2 sids x 576 q x 64 l
    int sid = idx / 36864;
    int rem = idx - sid * 36864;
    int q = rem >> 6, l = rem & 63;
    int nc = q & 3, t9 = q >> 2;
    int j = t9 % 9, ds = t9 / 9;
    const float* bw = sid ? bw1y : bw1x;
    const float* sw = sid ? sw1y : sw1x;
    uint4* dst = sid ? B1fy : B1fx;
    int o = nc * 32 + (l & 31);
    int dbase = ds * 16 + (l >> 5) * 8;
    unsigned short eh[8];
    #pragma unroll
    for (int i = 0; i < 8; ++i) {
      int d = dbase + i;
      float wv = (j == 0) ? bw[o * 256 + d] : sw[o * 2048 + d * 8 + (j - 1)];
      eh[i] = f2bf(wv);
    }
    uint4 oh;
    oh.x = (unsigned)eh[0] | ((unsigned)eh[1] << 16);
    oh.y = (unsigned)eh[2] | ((unsigned)eh[3] << 16);
    oh.z = (unsigned)eh[4] | ((unsigned)eh[5] << 16);
    oh.w = (unsigned)eh[6] | ((unsigned)eh[7] << 16);
    dst[q * 64 + l] = oh;
  } else if (idx < 2 * 36864 + 2 * 9216) {     // B2: 2 sids x 144 q2 x 64 l
    int i2 = idx - 2 * 36864;
    int sid = i2 / 9216;
    int rem = i2 - sid * 9216;
    int q2 = rem >> 6, l = rem & 63;
    int nc = q2 & 1, t9 = q2 >> 1;
    int j = t9 % 9, w = t9 / 9;
    const float* bw = sid ? bw2y : bw2x;
    const float* sw = sid ? sw2y : sw2x;
    uint4* dst = sid ? B2fy : B2fx;
    int o = nc * 32 + (l & 31);
    int dbase = w * 16 + (l >> 5) * 8;
    unsigned short eh[8];
    #pragma unroll
    for (int i = 0; i < 8; ++i) {
      int d = dbase + i;
      float wv = (j == 0) ? bw[o * 128 + d] : sw[o * 1024 + d * 8 + (j - 1)];
      eh[i] = f2bf(wv);
    }
    uint4 oh;
    oh.x = (unsigned)eh[0] | ((unsigned)eh[1] << 16);
    oh.y = (unsigned)eh[2] | ((unsigned)eh[3] << 16);
    oh.z = (unsigned)eh[4] | ((unsigned)eh[5] << 16);
    oh.w = (unsigned)eh[6] | ((unsigned)eh[7] << 16);
    dst[q2 * 64 + l] = oh;
  } else {
    int i2 = idx - (2 * 36864 + 2 * 9216);
    if (i2 < 128)      b1x[i2]       = bb1x[i2]       + sb1x[i2];
    else if (i2 < 256) b1y[i2 - 128] = bb1y[i2 - 128] + sb1y[i2 - 128];
    else if (i2 < 320) b2x[i2 - 256] = bb2x[i2 - 256] + sb2x[i2 - 256];
    else if (i2 < 384) b2y[i2 - 320] = bb2y[i2 - 320] + sb2y[i2 - 320];
    else if (i2 < 388) cnt[i2 - 384] = 0;
  }
}

// ---------- fused: both layers + last-block finish; block = (sid, 32-row tile m)
__global__ __launch_bounds__(512, 2) void fused_kernel(
    const float* __restrict__ Xx, const float* __restrict__ Xy,
    const uint4* __restrict__ B1fx, const uint4* __restrict__ B1fy,
    const uint4* __restrict__ B2fx, const uint4* __restrict__ B2fy,
    const float* __restrict__ b1x_, const float* __restrict__ b1y_,
    const float* __restrict__ b2x_, const float* __restrict__ b2y_,
    const float* __restrict__ finw, const float* __restrict__ finb,
    float* __restrict__ partial, int* __restrict__ cnt,
    float* __restrict__ out)
{
  __shared__ __align__(16) char smem[51232];
  float* xsh  = (float*)smem;               // 32*264 floats = 33792 B
  float* S0   = (float*)smem;               // 16 KB (alias; used after xr read)
  float* S1   = (float*)(smem + 16384);     // 16 KB
  float* h1s  = (float*)(smem + 33792);     // 32*136 floats = 17408 B
  float* redw = (float*)(smem + 51200);     // 8 floats

  const int t    = threadIdx.x;
  const int bid  = blockIdx.x;
  const int sid  = bid >> 7;
  const int m    = bid & 127;
  const int wave = t >> 6;
  const int l    = t & 63;
  const int lc   = l & 31;
  const int lk   = l >> 5;

  const float* X  = sid ? Xy : Xx;
  const uint4* B1 = sid ? B1fy : B1fx;
  const uint4* B2 = sid ? B2fy : B2fx;
  const float* b1 = sid ? b1y_ : b1x_;
  const float* b2 = sid ? b2y_ : b2x_;

  // ---- stage x tile: 32 rows x 256, coalesced ----
  {
    int row = t >> 4, col = (t & 15) * 16;
    const float* src = X + (size_t)(m * 32 + row) * 256 + col;
    #pragma unroll
    for (int q = 0; q < 4; ++q)
      *(float4*)(xsh + row * 264 + col + q * 4) = *(const float4*)(src + q * 4);
  }
  __syncthreads();

  // per-lane A data: row lc, dims for ds0 = 2*wave and ds1 = 2*wave+1
  float xr0[8], xr1[8];
  {
    int cb = wave * 32 + lk * 8;
    float4 v0 = *(const float4*)(xsh + lc * 264 + cb);
    float4 v1 = *(const float4*)(xsh + lc * 264 + cb + 4);
    float4 u0 = *(const float4*)(xsh + lc * 264 + cb + 16);
    float4 u1 = *(const float4*)(xsh + lc * 264 + cb + 20);
    xr0[0]=v0.x; xr0[1]=v0.y; xr0[2]=v0.z; xr0[3]=v0.w;
    xr0[4]=v1.x; xr0[5]=v1.y; xr0[6]=v1.z; xr0[7]=v1.w;
    xr1[0]=u0.x; xr1[1]=u0.y; xr1[2]=u0.z; xr1[3]=u0.w;
    xr1[4]=u1.x; xr1[5]=u1.y; xr1[6]=u1.z; xr1[7]=u1.w;
  }
  __syncthreads();   // xsh dead; S0/S1 free

  // ================= layer 1: 18 steps (9 j x 2 ds), 1-step lookahead ========
  floatx16 acc[4] = {};

  auto loadB1 = [&](int s, uint4* bf) {
    int j = s >> 1, ds = wave * 2 + (s & 1);
    const uint4* bp = B1 + (size_t)((ds * 9 + j) * 4) * 64 + l;
    #pragma unroll
    for (int nc = 0; nc < 4; ++nc) bf[nc] = bp[nc * 64];
  };
  auto computeB1 = [&](int s, const uint4* bf) {
    int j = s >> 1;
    const float* xr = (s & 1) ? xr1 : xr0;
    float f[8];
    if (j == 0) {
      #pragma unroll
      for (int i = 0; i < 8; ++i)
        f[i] = __fdividef(xr[i], 1.f + __expf(-xr[i]));
    } else {
      float g = -2.f + (float)(j - 1) * (4.f / 7.f);
      #pragma unroll
      for (int i = 0; i < 8; ++i) {
        float z = (xr[i] - g) * 1.75f;
        f[i] = __expf(-z * z);
      }
    }
    short8 a;
    #pragma unroll
    for (int i = 0; i < 8; ++i) a[i] = (short)f2bf(f[i]);
    #pragma unroll
    for (int nc = 0; nc < 4; ++nc) {
      short8 bh = __builtin_bit_cast(short8, bf[nc]);
      acc[nc] = __builtin_amdgcn_mfma_f32_32x32x16_bf16(a, bh, acc[nc], 0, 0, 0);
    }
  };

  {
    uint4 bfE[4], bfO[4];
    loadB1(0, bfE);
    #pragma unroll 1
    for (int s = 0; s < 18; s += 2) {
      loadB1(s + 1, bfO);
      computeB1(s, bfE);
      if (s + 2 < 18) loadB1(s + 2, bfE);
      computeB1(s + 1, bfO);
    }
  }

  // ---- cross-wave K reduction: race-free 2-buffer tree (32x128 tile) ----
  auto st = [&](float* Sb) {
    #pragma unroll
    for (int nc = 0; nc < 4; ++nc)
      #pragma unroll
      for (int r = 0; r < 16; ++r) {
        int row = (r & 3) + 8 * (r >> 2) + 4 * lk;
        Sb[row * 128 + nc * 32 + lc] = acc[nc][r];
      }
  };
  auto ad = [&](const float* Sb) {
    #pragma unroll
    for (int nc = 0; nc < 4; ++nc)
      #pragma unroll
      for (int r = 0; r < 16; ++r) {
        int row = (r & 3) + 8 * (r >> 2) + 4 * lk;
        acc[nc][r] += Sb[row * 128 + nc * 32 + lc];
      }
  };
  __syncthreads();
  if (wave == 1) st(S0);
  if (wave == 3) st(S1);
  __syncthreads();
  if (wave == 0) ad(S0);
  if (wave == 2) ad(S1);
  __syncthreads();
  if (wave == 5) st(S0);
  if (wave == 7) st(S1);
  __syncthreads();
  if (wave == 4) ad(S0);
  if (wave == 6) ad(S1);
  __syncthreads();
  if (wave == 2) st(S0);
  if (wave == 6) st(S1);
  __syncthreads();
  if (wave == 0) ad(S0);
  if (wave == 4) ad(S1);
  __syncthreads();
  if (wave == 4) st(S0);
  __syncthreads();
  if (wave == 0) {
    ad(S0);
    #pragma unroll
    for (int nc = 0; nc < 4; ++nc)
      #pragma unroll
      for (int r = 0; r < 16; ++r) {
        int row = (r & 3) + 8 * (r >> 2) + 4 * lk;
        int col = nc * 32 + lc;
        h1s[row * 136 + col] = acc[nc][r] + b1[col];
      }
  }
  __syncthreads();

  // ================= layer 2: 9 steps, 1-step lookahead =================
  floatx16 acc2[2] = {};

  auto loadB2 = [&](int s, uint4* cf) {
    const uint4* bp = B2 + (size_t)((wave * 9 + s) * 2) * 64 + l;
    #pragma unroll
    for (int nc = 0; nc < 2; ++nc) cf[nc] = bp[nc * 64];
  };

  uint4 cfE[2], cfO[2];
  loadB2(0, cfE);              // issue before h1 read; independent

  float hr[8];
  {
    int cb = wave * 16 + lk * 8;
    float4 v0 = *(const float4*)(h1s + lc * 136 + cb);
    float4 v1 = *(const float4*)(h1s + lc * 136 + cb + 4);
    hr[0]=v0.x; hr[1]=v0.y; hr[2]=v0.z; hr[3]=v0.w;
    hr[4]=v1.x; hr[5]=v1.y; hr[6]=v1.z; hr[7]=v1.w;
  }

  auto computeB2 = [&](int s, const uint4* cf) {
    float f[8];
    if (s == 0) {
      #pragma unroll
      for (int i = 0; i < 8; ++i)
        f[i] = __fdividef(hr[i], 1.f + __expf(-hr[i]));
    } else {
      float g = -2.f + (float)(s - 1) * (4.f / 7.f);
      #pragma unroll
      for (int i = 0; i < 8; ++i) {
        float z = (hr[i] - g) * 1.75f;
        f[i] = __expf(-z * z);
      }
    }
    short8 a;
    #pragma unroll
    for (int i = 0; i < 8; ++i) a[i] = (short)f2bf(f[i]);
    #pragma unroll
    for (int nc = 0; nc < 2; ++nc) {
      short8 bh = __builtin_bit_cast(short8, cf[nc]);
      acc2[nc] = __builtin_amdgcn_mfma_f32_32x32x16_bf16(a, bh, acc2[nc], 0, 0, 0);
    }
  };

  #pragma unroll 1
  for (int s = 0; s < 8; s += 2) {
    loadB2(s + 1, cfO);
    computeB2(s, cfE);
    loadB2(s + 2, cfE);
    computeB2(s + 1, cfO);
  }
  computeB2(8, cfE);

  // ---- per-wave dot with final_w; cross-wave scalar sum ----
  const float* wf = finw + sid * 64;
  {
    float w0 = wf[lc], w1v = wf[32 + lc];
    float pz = 0.f;
    #pragma unroll
    for (int r = 0; r < 16; ++r) pz += acc2[0][r] * w0 + acc2[1][r] * w1v;
    #pragma unroll
    for (int off = 32; off > 0; off >>= 1) pz += __shfl_down(pz, off, 64);
    if (l == 0) redw[wave] = pz;
  }
  __syncthreads();

  // ---- block partial + last-block-per-batch finish ----
  if (wave == 0) {
    const int b    = m >> 5;                 // batch
    const int slot = sid * 32 + (m & 31);    // 64 slots per batch
    float v = (l < 8) ? redw[l] : 0.f;
    v += 32.f * b2[l] * wf[l];               // bias term over this block's 32 rows
    #pragma unroll
    for (int off = 32; off > 0; off >>= 1) v += __shfl_down(v, off, 64);
    int old = 0;
    if (l == 0) {
      partial[b * 64 + slot] = v;
      __threadfence();
      old = atomicAdd(&cnt[b], 1);
    }
    int bc = __shfl(old, 0, 64);
    if (bc == 63) {                          // last block of this batch
      float pv = atomicAdd(&partial[b * 64 + l], 0.f);  // coherent read
      #pragma unroll
      for (int off = 32; off > 0; off >>= 1) pv += __shfl_down(pv, off, 64);
      if (l == 0) out[b] = finb[0] + pv * (1.0f / 1024.0f);
    }
  }
}

extern "C" void kernel_launch(void* const* d_in, const int* in_sizes, int n_in,
                              void* d_out, int out_size, void* d_ws, size_t ws_size,
                              hipStream_t stream)
{
  (void)in_sizes; (void)n_in; (void)out_size; (void)ws_size;
  const float* x    = (const float*)d_in[0];
  const float* y    = (const float*)d_in[1];
  const float* bw1x = (const float*)d_in[2];
  const float* bb1x = (const float*)d_in[3];
  const float* sw1x = (const float*)d_in[4];
  const float* sb1x = (const float*)d_in[5];
  const float* bw2x = (const float*)d_in[6];
  const float* bb2x = (const float*)d_in[7];
  const float* sw2x = (const float*)d_in[8];
  const float* sb2x = (const float*)d_in[9];
  const float* bw1y = (const float*)d_in[10];
  const float* bb1y = (const float*)d_in[11];
  const float* sw1y = (const float*)d_in[12];
  const float* sb1y = (const float*)d_in[13];
  const float* bw2y = (const float*)d_in[14];
  const float* bb2y = (const float*)d_in[15];
  const float* sw2y = (const float*)d_in[16];
  const float* sb2y = (const float*)d_in[17];
  const float* finw = (const float*)d_in[18];
  const float* finb = (const float*)d_in[19];

  char* ws = (char*)d_ws;
  uint4* B1fx = (uint4*)(ws);                       // 589824 B
  uint4* B1fy = (uint4*)(ws + 589824);
  uint4* B2fx = (uint4*)(ws + 1179648);             // 147456 B
  uint4* B2fy = (uint4*)(ws + 1327104);
  float* b1x  = (float*)(ws + 1474560);
  float* b1y  = b1x + 128;
  float* b2x  = b1y + 128;
  float* b2y  = b2x + 64;
  float* partial = b2y + 64;                        // 256 floats
  int*   cnt  = (int*)(partial + 256);              // 4 ints

  int prep_total = 2 * 36864 + 2 * 9216 + 388;      // 92548
  int prep_blocks = (prep_total + 511) / 512;
  hipLaunchKernelGGL(prep_frags, dim3(prep_blocks), dim3(512), 0, stream,
                     bw1x, sw1x, bb1x, sb1x, bw2x, sw2x, bb2x, sb2x,
                     bw1y, sw1y, bb1y, sb1y, bw2y, sw2y, bb2y, sb2y,
                     B1fx, B1fy, B2fx, B2fy, b1x, b1y, b2x, b2y, cnt);

  hipLaunchKernelGGL(fused_kernel, dim3(256), dim3(512), 0, stream,
                     x, y, B1fx, B1fy, B2fx, B2fy, b1x, b1y, b2x, b2y,
                     finw, finb, partial, cnt, (float*)d_out);
}